// Round 9
// baseline (253.353 us; speedup 1.0000x reference)
//
#include <hip/hip_runtime.h>

typedef _Float16 half_t;
typedef __attribute__((ext_vector_type(8))) _Float16 h8;
typedef __attribute__((ext_vector_type(2))) _Float16 h2v;
typedef __attribute__((ext_vector_type(4))) float f4;
typedef __attribute__((ext_vector_type(16))) float f16v;
typedef __attribute__((ext_vector_type(2))) float f2v;

// fp32 -> fp16 with inf/NaN killing (fmaxf/fminf return the non-NaN operand).
__device__ __forceinline__ half_t to_h(float v) {
    v = fminf(fmaxf(v, -60000.f), 60000.f);
    return (half_t)v;
}

// ---------------- pack kernel: fp32 weights -> fp16 MFMA-B frags (32x32x16 layout) -------
// ws layout (half elements):
//   w1p: [0, 524288)          [ks=128][nt=8][lane=64][j=8]  n-tile width 32
//   w2p: [524288, 557056)     [ks=16][nt=4][64][8]
//   swp: [557056, 622592)     [ks=32][nt=4][64][8]
//   cwp: [622592, 630912)     [p=k*13+ip][c=64][r=2]
// B element: lane L holds n = nt*32 + (L&31), k = ks*16 + (L>>5)*8 + j.
__global__ void pack_k(const float* __restrict__ w1, const float* __restrict__ w2,
                       const float* __restrict__ sw, const float* __restrict__ cw,
                       half_t* __restrict__ wsH) {
    int i = blockIdx.x * 256 + threadIdx.x;
    if (i < 65536) {                        // w1 [2048][256]
        int L = i & 63, nt = (i >> 6) & 7, ks = i >> 9;
        int k0 = ks * 16 + ((L >> 5) << 3), n = nt * 32 + (L & 31);
        h8 v;
#pragma unroll
        for (int j = 0; j < 8; j++) v[j] = to_h(w1[(k0 + j) * 256 + n]);
        *(h8*)(wsH + ((size_t)i << 3)) = v;
    } else if (i < 69632) {                 // w2 [256][128]
        int o = i - 65536;
        int L = o & 63, nt = (o >> 6) & 3, ks = o >> 8;
        int k0 = ks * 16 + ((L >> 5) << 3), n = nt * 32 + (L & 31);
        h8 v;
#pragma unroll
        for (int j = 0; j < 8; j++) v[j] = to_h(w2[(k0 + j) * 128 + n]);
        *(h8*)(wsH + 524288 + ((size_t)o << 3)) = v;
    } else if (i < 77824) {                 // sw [512][128]
        int o = i - 69632;
        int L = o & 63, nt = (o >> 6) & 3, ks = o >> 8;
        int k0 = ks * 16 + ((L >> 5) << 3), n = nt * 32 + (L & 31);
        h8 v;
#pragma unroll
        for (int j = 0; j < 8; j++) v[j] = to_h(sw[(k0 + j) * 128 + n]);
        *(h8*)(wsH + 557056 + ((size_t)o << 3)) = v;
    } else if (i < 86144) {                 // cw [5][26][64]
        int o = i - 77824;
        int c = o & 63, rest = o >> 6;
        int k = rest / 26, ci = rest - k * 26;
        int ip = ci >> 1, r = ci & 1;
        wsH[622592 + ((k * 13 + ip) * 64 + c) * 2 + r] = to_h(cw[o]);
    }
}

// ---------------- main fused kernel ----------------
// block = 512 thr (8 waves), one b and 64 consecutive t. Grid = 512 (2 blocks/CU, grid-capped).
// All GEMMs on mfma_f32_32x32x16_f16: halves LDS-A traffic per FLOP vs 16x16x32.
// XCS/ALS = 68 halfs (34 dwords): 32-row lane reads alias 2-way only (free per m136).
#define XCS 68
#define ALS 68
#define Y1S 264
#define SLS 68
#define HLS 20

#define MFMA32(a, b, c) __builtin_amdgcn_mfma_f32_32x32x16_f16(a, b, c, 0, 0, 0)

__global__ __launch_bounds__(512, 4) void beat_main(
    const float* __restrict__ x,
    const float* __restrict__ conv_b,
    const float* __restrict__ se_w1, const float* __restrict__ se_b1,
    const float* __restrict__ se_w2, const float* __restrict__ se_b2,
    const float* __restrict__ b1, const float* __restrict__ b2,
    const float* __restrict__ sb,
    const float* __restrict__ wo, const float* __restrict__ bo,
    const half_t* __restrict__ w1p, const half_t* __restrict__ w2p,
    const half_t* __restrict__ swp, const half_t* __restrict__ cwp,
    float* __restrict__ out) {

    // xcL [0,12928) 95x68 halfs | aL [12928,21632) 64x68 halfs |
    // U [21632,55424): xLh (0a-0b) / sLf+hidL (1a-1c) / y1L 64x264 (2..5b) | woL [55424,57472)
    __shared__ __align__(16) char smem[57472];
    half_t* xcL = (half_t*)smem;
    half_t* aL  = (half_t*)(smem + 12928);
    char*   U   = smem + 21632;
    half_t* xLh = (half_t*)U;
    float*  sLf = (float*)U;
    float*  hidL= (float*)(smem + 39040);
    half_t* y1L = (half_t*)U;
    float*  woL = (float*)(smem + 55424);

    const int tid = threadIdx.x;
    const int bi = blockIdx.x;
    const int b = bi >> 6;
    const int t0 = (bi & 63) << 6;
    const int lane = tid & 63, wv = tid >> 6;     // wv in 0..7
    const int l31 = lane & 31, khalf = lane >> 5; // 32x32 fragment coords

    // ---- phase 0a: stage x (fp16 pairs) + wo ----
    if (tid < 256) ((f2v*)woL)[tid] = ((const f2v*)wo)[tid];   // 512 floats
    for (int idx = tid; idx < 99 * 13; idx += 512) {
        int fi = idx / 13, ip = idx - fi * 13;
        int tx = t0 - 35 + fi;
        h2v v;
        if (tx >= 0) {
            const float* xp = x + ((size_t)(b * 4096 + tx)) * 26 + 2 * ip;
            v[0] = to_h(xp[0]); v[1] = to_h(xp[1]);
        } else { v[0] = (_Float16)0.f; v[1] = (_Float16)0.f; }
        *(h2v*)(xLh + fi * 28 + 2 * ip) = v;
    }
    __syncthreads();

    // ---- phase 0b: causal conv (K=5, 26->64) + relu -> xcL (fp16), 95 rows ----
    {
        int c = tid & 63, f0 = tid >> 6;          // f0 in 0..7
        h2v cwr[65];
        const h2v* cwg = (const h2v*)cwp;         // coalesced b32 per lane
#pragma unroll
        for (int p = 0; p < 65; p++) cwr[p] = cwg[p * 64 + c];
        float bias = conv_b[c];
        for (int f = f0; f < 95; f += 8) {
            int t = t0 - 31 + f;
            float r0 = 0.f;
            if (t >= 0) {
                h2v accp; accp[0] = (_Float16)0.f; accp[1] = (_Float16)0.f;
#pragma unroll
                for (int k = 0; k < 5; k++)
#pragma unroll
                    for (int ip = 0; ip < 13; ip++) {
                        h2v xp = *(const h2v*)(xLh + (f + k) * 28 + 2 * ip);
                        accp += xp * cwr[k * 13 + ip];
                    }
                r0 = fmaxf((float)accp[0] + (float)accp[1] + bias, 0.f);
            }
            xcL[f * XCS + c] = to_h(r0);
        }
    }
    __syncthreads();

    // ---- phase 1a: sliding window means s[m][c], m in [0,64) ----
    {
        int c = tid & 63, mb = tid >> 6;          // mb in 0..7
        float run = 0.f;
#pragma unroll 8
        for (int w = 0; w < 32; w++) run += (float)xcL[(mb + w) * XCS + c];
        sLf[mb * SLS + c] = run * (1.f / 32.f);
        for (int m = mb + 8; m < 64; m += 8) {
#pragma unroll
            for (int d = 0; d < 8; d++) {
                run += (float)xcL[(m + 24 + d) * XCS + c];
                run -= (float)xcL[(m - 8 + d) * XCS + c];
            }
            sLf[m * SLS + c] = run * (1.f / 32.f);
        }
    }
    __syncthreads();

    // ---- phase 1b: SE hidden = relu(s @ se_w1 + se_b1), 64 m x 16 h ----
    {
        int m = tid >> 3, hh = (tid & 7) * 2;
        float acc0 = se_b1[hh], acc1 = se_b1[hh + 1];
        for (int c = 0; c < 64; c++) {
            float sv = sLf[m * SLS + c];
            f2v wq = *(const f2v*)(se_w1 + c * 16 + hh);
            acc0 += sv * wq[0]; acc1 += sv * wq[1];
        }
        hidL[m * HLS + hh] = fmaxf(acc0, 0.f);
        hidL[m * HLS + hh + 1] = fmaxf(acc1, 0.f);
    }
    __syncthreads();

    // ---- phase 1c: a = sigmoid(hidden @ se_w2 + se_b2) -> aL (fp16) ----
    {
        int m = tid >> 3, c0 = (tid & 7) * 8;
        float av[8];
#pragma unroll
        for (int j = 0; j < 8; j++) av[j] = se_b2[c0 + j];
        for (int h = 0; h < 16; h++) {
            float hv = hidL[m * HLS + h];
            const f4* wv4 = (const f4*)(se_w2 + h * 64 + c0);
            f4 wq0 = wv4[0], wq1 = wv4[1];
#pragma unroll
            for (int j = 0; j < 4; j++) { av[j] += hv * wq0[j]; av[4 + j] += hv * wq1[j]; }
        }
#pragma unroll
        for (int j = 0; j < 8; j++) {
            float zz = fminf(fmaxf(av[j], -30.f), 30.f);
            float s = 1.f / (1.f + __expf(-zz));
            aL[m * ALS + c0 + j] = to_h(s);
        }
    }
    __syncthreads();

    // ---- phase 2: y1 = relu((a .* window) @ w1 + b1), M=64 K=2048 N=256, 32x32x16 ----
    // wave wv: n-tile wv (cols wv*32..+32), both m-tiles. A lane: m=l31, k=khalf*8+j.
    {
        f16v acc0, acc1;
#pragma unroll
        for (int r = 0; r < 16; r++) { acc0[r] = 0.f; acc1[r] = 0.f; }
        // gates in registers: avr[m32][s] = a[m32*32+l31][s*16 + khalf*8 ..+8]
        h8 avr[2][4];
#pragma unroll
        for (int m32 = 0; m32 < 2; m32++)
#pragma unroll
            for (int s = 0; s < 4; s++)
                avr[m32][s] = *(const h8*)(aL + (m32 * 32 + l31) * ALS + s * 16 + khalf * 8);
        const h8* bp = ((const h8*)w1p) + wv * 64 + lane;   // frag(ks) = bp[ks*512]
        h8 bP0 = bp[0], bP1 = bp[512];
        const half_t* xr0 = xcL + l31 * XCS + khalf * 8;
        const half_t* xr1 = xcL + (32 + l31) * XCS + khalf * 8;
        for (int q = 0; q < 32; q++) {      // quad of ks; wf = q, c-slice = (ks&3)*16
            h8 bN0 = bp[(q * 4 + 2) * 512];
            {
                h8 x0 = *(const h8*)(xr0), x1 = *(const h8*)(xr1);
                acc0 = MFMA32(x0 * avr[0][0], bP0, acc0);
                acc1 = MFMA32(x1 * avr[1][0], bP0, acc1);
            }
            h8 bN1 = bp[(q * 4 + 3) * 512];
            {
                h8 x0 = *(const h8*)(xr0 + 16), x1 = *(const h8*)(xr1 + 16);
                acc0 = MFMA32(x0 * avr[0][1], bP1, acc0);
                acc1 = MFMA32(x1 * avr[1][1], bP1, acc1);
            }
            bP0 = bp[((q * 4 + 4) & 127) * 512];
            {
                h8 x0 = *(const h8*)(xr0 + 32), x1 = *(const h8*)(xr1 + 32);
                acc0 = MFMA32(x0 * avr[0][2], bN0, acc0);
                acc1 = MFMA32(x1 * avr[1][2], bN0, acc1);
            }
            bP1 = bp[((q * 4 + 5) & 127) * 512];
            {
                h8 x0 = *(const h8*)(xr0 + 48), x1 = *(const h8*)(xr1 + 48);
                acc0 = MFMA32(x0 * avr[0][3], bN1, acc0);
                acc1 = MFMA32(x1 * avr[1][3], bN1, acc1);
            }
            xr0 += XCS; xr1 += XCS;
        }
        // epilogue: C/D map col=l31, row=(r&3)+8*(r>>2)+4*khalf
        int n = wv * 32 + l31;
        float bb = b1[n];
#pragma unroll
        for (int r = 0; r < 16; r++) {
            int row = (r & 3) + 8 * (r >> 2) + 4 * khalf;
            y1L[row * Y1S + n]        = to_h(fmaxf(acc0[r] + bb, 0.f));
            y1L[(32 + row) * Y1S + n] = to_h(fmaxf(acc1[r] + bb, 0.f));
        }
    }
    __syncthreads();

    // ---- phase 3: h2 = relu(y1 @ w2 + b2), M=64 K=256 N=128, 32x32x16 ----
    // wave wv: m-tile wv>>2, n-tile wv&3.
    f16v acc2;
#pragma unroll
    for (int r = 0; r < 16; r++) acc2[r] = 0.f;
    {
        const int m32 = wv >> 2, nt = wv & 3;
        const h8* bp2 = ((const h8*)w2p) + nt * 64 + lane;   // frag(ks) = bp2[ks*256]
        const half_t* ar = y1L + (m32 * 32 + l31) * Y1S + khalf * 8;
        h8 bc = bp2[0];
#pragma unroll 2
        for (int ks = 0; ks < 16; ks++) {
            h8 bn = bp2[((ks + 1) & 15) * 256];
            h8 av = *(const h8*)(ar + ks * 16);
            acc2 = MFMA32(av, bc, acc2);
            bc = bn;
        }
    }

    // ---- phase 4: h_short = relu((a .* window[-8:]) @ sw + sb), K=512 N=128, 32x32x16 ----
    f16v accS;
#pragma unroll
    for (int r = 0; r < 16; r++) accS[r] = 0.f;
    {
        const int m32 = wv >> 2, nt = wv & 3;
        const h8* bps = ((const h8*)swp) + nt * 64 + lane;   // frag(ks) = bps[ks*256]
        const half_t* arow = aL + (m32 * 32 + l31) * ALS + khalf * 8;
        const half_t* xrow = xcL + (m32 * 32 + l31) * XCS + khalf * 8;
        h8 bc = bps[0];
#pragma unroll 2
        for (int ks = 0; ks < 32; ks++) {
            h8 bn = bps[((ks + 1) & 31) * 256];
            const int wf = 24 + (ks >> 2);
            const int c0 = (ks & 3) * 16;
            h8 xv = *(const h8*)(xrow + wf * XCS + c0);
            h8 gv = *(const h8*)(arow + c0);
            accS = MFMA32(xv * gv, bc, accS);
            bc = bn;
        }
    }
    __syncthreads();  // phase-3 reads of y1L complete before overwrite

    // ---- phase 5a: hL[m][0:128]=relu(h2), hL[m][128:256]=relu(h_short) ----
    {
        const int m32 = wv >> 2, nt = wv & 3;
        int n = nt * 32 + l31;
        float bb2 = b2[n], bbs = sb[n];
#pragma unroll
        for (int r = 0; r < 16; r++) {
            int m = m32 * 32 + (r & 3) + 8 * (r >> 2) + 4 * khalf;
            y1L[m * Y1S + n]       = to_h(fmaxf(acc2[r] + bb2, 0.f));
            y1L[m * Y1S + 128 + n] = to_h(fmaxf(accS[r] + bbs, 0.f));
        }
    }
    __syncthreads();

    // ---- phase 5b: out = sigmoid(h @ wo + bo), 128 threads ----
    if (tid < 128) {
        int m = tid >> 1, o = tid & 1;
        float z = bo[o];
        const half_t* hrow = y1L + m * Y1S;
        for (int nb = 0; nb < 32; nb++) {
            h8 hv = *(const h8*)(hrow + nb * 8);
#pragma unroll
            for (int q = 0; q < 8; q++)
                z += (float)hv[q] * woL[(nb * 8 + q) * 2 + o];
        }
        z = fminf(fmaxf(z, -30.f), 30.f);
        float sg = 1.f / (1.f + __expf(-z));
        out[((size_t)(b * 4096 + t0 + m)) * 2 + o] = sg;
    }
}

extern "C" void kernel_launch(void* const* d_in, const int* in_sizes, int n_in,
                              void* d_out, int out_size, void* d_ws, size_t ws_size,
                              hipStream_t stream) {
    const float* x      = (const float*)d_in[0];
    const float* conv_w = (const float*)d_in[1];
    const float* conv_b = (const float*)d_in[2];
    const float* se_w1  = (const float*)d_in[3];
    const float* se_b1  = (const float*)d_in[4];
    const float* se_w2  = (const float*)d_in[5];
    const float* se_b2  = (const float*)d_in[6];
    const float* w1     = (const float*)d_in[7];
    const float* b1     = (const float*)d_in[8];
    const float* w2     = (const float*)d_in[9];
    const float* b2     = (const float*)d_in[10];
    const float* sw     = (const float*)d_in[11];
    const float* sb     = (const float*)d_in[12];
    const float* wo     = (const float*)d_in[13];
    const float* bo     = (const float*)d_in[14];
    half_t* wsH = (half_t*)d_ws;

    hipLaunchKernelGGL(pack_k, dim3(337), dim3(256), 0, stream, w1, w2, sw, conv_w, wsH);
    hipLaunchKernelGGL(beat_main, dim3(512), dim3(512), 0, stream,
                       x, conv_b, se_w1, se_b1, se_w2, se_b2, b1, b2, sb, wo, bo,
                       wsH, wsH + 524288, wsH + 557056, wsH + 622592,
                       (float*)d_out);
}

// Round 10
// 144.656 us; speedup vs baseline: 1.7514x; 1.7514x over previous
//
#include <hip/hip_runtime.h>

typedef _Float16 half_t;
typedef __attribute__((ext_vector_type(8))) _Float16 h8;
typedef __attribute__((ext_vector_type(2))) _Float16 h2v;
typedef __attribute__((ext_vector_type(4))) float f4;
typedef __attribute__((ext_vector_type(2))) float f2v;

// fp32 -> fp16 with inf/NaN killing (fmaxf/fminf return the non-NaN operand).
__device__ __forceinline__ half_t to_h(float v) {
    v = fminf(fmaxf(v, -60000.f), 60000.f);
    return (half_t)v;
}

// ---------------- pack kernel: bilaterally-coalesced fp32 -> fp16 MFMA-B frags ----------
// ws layout (half elements):
//   w1p: [0, 524288)          [kk=64][nt=16][lane=64][j=8]
//   w2p: [524288, 557056)     [kk=8][nt=8][64][8]
//   swp: [557056, 622592)     [kk=16][nt=8][64][8]
//   cwp: [622592, 630912)     [p=k*13+ip][c=64][r=2]
__global__ void pack_k(const float* __restrict__ w1, const float* __restrict__ w2,
                       const float* __restrict__ sw, const float* __restrict__ cw,
                       half_t* __restrict__ wsH) {
    int i = blockIdx.x * 256 + threadIdx.x;
    if (i < 65536) {                        // w1 [2048][256]: 65536 h8 jobs
        int L = i & 63, nt = (i >> 6) & 15, kk = i >> 10;
        int k0 = kk * 32 + ((L >> 4) << 3), n = (nt << 4) + (L & 15);
        h8 v;
#pragma unroll
        for (int j = 0; j < 8; j++) v[j] = to_h(w1[(k0 + j) * 256 + n]);
        *(h8*)(wsH + ((((kk * 16 + nt) * 64 + L)) << 3)) = v;
    } else if (i < 69632) {                 // w2 [256][128]: 4096 jobs
        int o = i - 65536;
        int L = o & 63, nt = (o >> 6) & 7, kk = o >> 9;
        int k0 = kk * 32 + ((L >> 4) << 3), n = (nt << 4) + (L & 15);
        h8 v;
#pragma unroll
        for (int j = 0; j < 8; j++) v[j] = to_h(w2[(k0 + j) * 128 + n]);
        *(h8*)(wsH + 524288 + ((((kk * 8 + nt) * 64 + L)) << 3)) = v;
    } else if (i < 77824) {                 // sw [512][128]: 8192 jobs
        int o = i - 69632;
        int L = o & 63, nt = (o >> 6) & 7, kk = o >> 9;
        int k0 = kk * 32 + ((L >> 4) << 3), n = (nt << 4) + (L & 15);
        h8 v;
#pragma unroll
        for (int j = 0; j < 8; j++) v[j] = to_h(sw[(k0 + j) * 128 + n]);
        *(h8*)(wsH + 557056 + ((((kk * 8 + nt) * 64 + L)) << 3)) = v;
    } else if (i < 86144) {                 // cw [5][26][64]: 8320 element jobs
        int o = i - 77824;
        int c = o & 63, rest = o >> 6;
        int k = rest / 26, ci = rest - k * 26;
        int ip = ci >> 1, r = ci & 1;
        wsH[622592 + ((k * 13 + ip) * 64 + c) * 2 + r] = to_h(cw[o]);
    }
}

// ---------------- main fused kernel (round-7 base; conv reads vectorized) ----------------
// block = 512 thr (8 waves), one b and 64 consecutive t. Grid = 8*64 = 512.
// NOTE (R9 post-mortem): mfma_f32_32x32x16 restructure ran 2.45x slower with all pipes
// idle (same absolute MFMA/VALU time, +110us stall) — stay on 16x16x32 with 8 acc chains.
#define XCS 72   // xcL row stride (halfs), 95 rows, frame f <-> t = t0-31+f
#define XLS 32   // xLh row stride (halfs), 64 B: rows 16B-aligned for ds_read_b128
#define ALS 72   // aL row stride (halfs), 64 rows
#define Y1S 264  // y1L / hL row stride (halfs), 64 rows
#define SLS 68   // sLf row stride (floats)
#define HLS 20   // hidL row stride (floats)

#define MFMA16(a, b, c) __builtin_amdgcn_mfma_f32_16x16x32_f16(a, b, c, 0, 0, 0)

__global__ __launch_bounds__(512, 4) void beat_main(
    const float* __restrict__ x,
    const float* __restrict__ conv_b,
    const float* __restrict__ se_w1, const float* __restrict__ se_b1,
    const float* __restrict__ se_w2, const float* __restrict__ se_b2,
    const float* __restrict__ b1, const float* __restrict__ b2,
    const float* __restrict__ sb,
    const float* __restrict__ wo, const float* __restrict__ bo,
    const half_t* __restrict__ w1p, const half_t* __restrict__ w2p,
    const half_t* __restrict__ swp, const half_t* __restrict__ cwp,
    float* __restrict__ out) {

    __shared__ __align__(16) char smem[58752];
    half_t* xcL = (half_t*)smem;             // 95*72*2 = 13680 -> pad 13696
    half_t* aL  = (half_t*)(smem + 13696);   // 64*72*2 = 9216 -> 22912
    char*   U   = smem + 22912;              // 33792-byte phase union
    half_t* xLh = (half_t*)U;                // phase0: 99*32 halfs = 6336
    float*  sLf = (float*)U;                 // phase1: 64*68 floats = 17408
    float*  hidL= (float*)(U + 17408);       // phase1: 64*20 floats = 5120
    half_t* y1L = (half_t*)U;                // phase2+: 64*264 halfs = 33792
    float*  woL = (float*)(smem + 56704);    // 512 floats -> 58752

    const int tid = threadIdx.x;
    const int bi = blockIdx.x;
    const int b = bi >> 6;
    const int t0 = (bi & 63) << 6;
    const int lane = tid & 63, wv = tid >> 6;     // wv in 0..7
    const int quad = lane >> 4, rl = lane & 15;

    // ---- phase 0a: stage x (fp16 pairs) + wo ----
    if (tid < 256) ((f2v*)woL)[tid] = ((const f2v*)wo)[tid];   // 512 floats
    for (int idx = tid; idx < 99 * 13; idx += 512) {
        int fi = idx / 13, ip = idx - fi * 13;
        int tx = t0 - 35 + fi;
        h2v v;
        if (tx >= 0) {
            const float* xp = x + ((size_t)(b * 4096 + tx)) * 26 + 2 * ip;
            v[0] = to_h(xp[0]); v[1] = to_h(xp[1]);
        } else { v[0] = (_Float16)0.f; v[1] = (_Float16)0.f; }
        *(h2v*)(xLh + fi * XLS + 2 * ip) = v;
    }
    __syncthreads();

    // ---- phase 0b: causal conv (K=5, 26->64) + relu -> xcL (fp16), 95 rows ----
    // Row reads vectorized: 3x ds_read_b128 + 1x b32 per tap-row (was 13x b32-class).
    {
        int c = tid & 63, f0 = tid >> 6;          // f0 in 0..7
        h2v cwr[65];
        const h2v* cwg = (const h2v*)cwp;         // coalesced b32 per lane
#pragma unroll
        for (int p = 0; p < 65; p++) cwr[p] = cwg[p * 64 + c];
        float bias = conv_b[c];
        for (int f = f0; f < 95; f += 8) {
            int t = t0 - 31 + f;
            float r0 = 0.f;
            if (t >= 0) {
                h2v accp; accp[0] = (_Float16)0.f; accp[1] = (_Float16)0.f;
#pragma unroll
                for (int k = 0; k < 5; k++) {
                    const half_t* rp = xLh + (f + k) * XLS;
                    h8 xa = *(const h8*)rp;
                    h8 xb = *(const h8*)(rp + 8);
                    h8 xc2 = *(const h8*)(rp + 16);
                    h2v xd = *(const h2v*)(rp + 24);
                    h2v xs[13];
#pragma unroll
                    for (int ii = 0; ii < 4; ii++) {
                        xs[ii][0]     = xa[2 * ii];  xs[ii][1]     = xa[2 * ii + 1];
                        xs[4 + ii][0] = xb[2 * ii];  xs[4 + ii][1] = xb[2 * ii + 1];
                        xs[8 + ii][0] = xc2[2 * ii]; xs[8 + ii][1] = xc2[2 * ii + 1];
                    }
                    xs[12] = xd;
#pragma unroll
                    for (int ip = 0; ip < 13; ip++)
                        accp += xs[ip] * cwr[k * 13 + ip];
                }
                r0 = fmaxf((float)accp[0] + (float)accp[1] + bias, 0.f);
            }
            xcL[f * XCS + c] = to_h(r0);
        }
    }
    __syncthreads();

    // ---- phase 1a: sliding window means s[m][c], m in [0,64) ----
    {
        int c = tid & 63, mb = tid >> 6;          // mb in 0..7
        float run = 0.f;
#pragma unroll 8
        for (int w = 0; w < 32; w++) run += (float)xcL[(mb + w) * XCS + c];
        sLf[mb * SLS + c] = run * (1.f / 32.f);
        for (int m = mb + 8; m < 64; m += 8) {
#pragma unroll
            for (int d = 0; d < 8; d++) {
                run += (float)xcL[(m + 24 + d) * XCS + c];
                run -= (float)xcL[(m - 8 + d) * XCS + c];
            }
            sLf[m * SLS + c] = run * (1.f / 32.f);
        }
    }
    __syncthreads();

    // ---- phase 1b: SE hidden = relu(s @ se_w1 + se_b1), 64 m x 16 h ----
    {
        int m = tid >> 3, hh = (tid & 7) * 2;
        float acc0 = se_b1[hh], acc1 = se_b1[hh + 1];
        for (int c = 0; c < 64; c++) {
            float sv = sLf[m * SLS + c];
            f2v wq = *(const f2v*)(se_w1 + c * 16 + hh);
            acc0 += sv * wq[0]; acc1 += sv * wq[1];
        }
        hidL[m * HLS + hh] = fmaxf(acc0, 0.f);
        hidL[m * HLS + hh + 1] = fmaxf(acc1, 0.f);
    }
    __syncthreads();

    // ---- phase 1c: a = sigmoid(hidden @ se_w2 + se_b2) -> aL (fp16) ----
    {
        int m = tid >> 3, c0 = (tid & 7) * 8;
        float av[8];
#pragma unroll
        for (int j = 0; j < 8; j++) av[j] = se_b2[c0 + j];
        for (int h = 0; h < 16; h++) {
            float hv = hidL[m * HLS + h];
            const f4* wv4 = (const f4*)(se_w2 + h * 64 + c0);
            f4 wq0 = wv4[0], wq1 = wv4[1];
#pragma unroll
            for (int j = 0; j < 4; j++) { av[j] += hv * wq0[j]; av[4 + j] += hv * wq1[j]; }
        }
#pragma unroll
        for (int j = 0; j < 8; j++) {
            float zz = fminf(fmaxf(av[j], -30.f), 30.f);
            float s = 1.f / (1.f + __expf(-zz));
            aL[m * ALS + c0 + j] = to_h(s);
        }
    }
    __syncthreads();

    // ---- gates into registers: avr[mt][half], rows mt*16+rl, channels half*32+quad*8 ----
    h8 avr[4][2];
#pragma unroll
    for (int mt = 0; mt < 4; mt++)
#pragma unroll
        for (int p = 0; p < 2; p++)
            avr[mt][p] = *(const h8*)(aL + (mt * 16 + rl) * ALS + p * 32 + quad * 8);

    // ---- phase 2: y1 = relu((a .* window) @ w1 + b1), M=64 K=2048 N=256 ----
    // wave wv: all 64 rows, cols wv*32..+32 (nt = wv*2+i). Prefetch distance 2 kk-steps.
    {
        f4 acc[4][2];
#pragma unroll
        for (int mt = 0; mt < 4; mt++)
#pragma unroll
            for (int i = 0; i < 2; i++)
#pragma unroll
                for (int r = 0; r < 4; r++) acc[mt][i][r] = 0.f;
        const h8* w1v = (const h8*)w1p;
        const int fb = wv * 2;
        h8 bA[2], bB[2], bC[2], bD[2];
#pragma unroll
        for (int i = 0; i < 2; i++) bA[i] = w1v[(fb + i) * 64 + lane];
#pragma unroll
        for (int i = 0; i < 2; i++) bB[i] = w1v[(16 + fb + i) * 64 + lane];
#pragma unroll 2
        for (int kk = 0; kk < 64; kk += 2) {
            const int k2 = (kk + 2) & 63, k3 = (kk + 3) & 63;  // wrap harmless on last iter
#pragma unroll
            for (int i = 0; i < 2; i++) bC[i] = w1v[(k2 * 16 + fb + i) * 64 + lane];
#pragma unroll
            for (int i = 0; i < 2; i++) bD[i] = w1v[(k3 * 16 + fb + i) * 64 + lane];
            const int wf = kk >> 1;
            {   // even kk: channels 0..31 -> avr[.][0]
                const int c0 = quad * 8;
#pragma unroll
                for (int mt = 0; mt < 4; mt++) {
                    int m = mt * 16 + rl;
                    h8 xv = *(const h8*)(xcL + (m + wf) * XCS + c0);
                    h8 af = xv * avr[mt][0];
                    acc[mt][0] = MFMA16(af, bA[0], acc[mt][0]);
                    acc[mt][1] = MFMA16(af, bA[1], acc[mt][1]);
                }
            }
            {   // odd kk: channels 32..63 -> avr[.][1]
                const int c0 = 32 + quad * 8;
#pragma unroll
                for (int mt = 0; mt < 4; mt++) {
                    int m = mt * 16 + rl;
                    h8 xv = *(const h8*)(xcL + (m + wf) * XCS + c0);
                    h8 af = xv * avr[mt][1];
                    acc[mt][0] = MFMA16(af, bB[0], acc[mt][0]);
                    acc[mt][1] = MFMA16(af, bB[1], acc[mt][1]);
                }
            }
#pragma unroll
            for (int i = 0; i < 2; i++) { bA[i] = bC[i]; bB[i] = bD[i]; }
        }
#pragma unroll
        for (int i = 0; i < 2; i++) {
            int n = wv * 32 + i * 16 + rl;
            float bb = b1[n];
#pragma unroll
            for (int mt = 0; mt < 4; mt++)
#pragma unroll
                for (int r = 0; r < 4; r++) {
                    int m = mt * 16 + quad * 4 + r;
                    y1L[m * Y1S + n] = to_h(fmaxf(acc[mt][i][r] + bb, 0.f));
                }
        }
    }
    __syncthreads();

    // ---- phase 3: h2 = relu(y1 @ w2 + b2), M=64 K=256 N=128; wave wv: cols wv*16..+16 ----
    f4 acc2[4];
#pragma unroll
    for (int mt = 0; mt < 4; mt++)
#pragma unroll
        for (int r = 0; r < 4; r++) acc2[mt][r] = 0.f;
    {
        const h8* w2v = (const h8*)w2p;
        h8 cf = w2v[wv * 64 + lane];
#pragma unroll 2
        for (int kk = 0; kk < 8; kk++) {
            int kn = (kk + 1) & 7;
            h8 nf = w2v[(kn * 8 + wv) * 64 + lane];
#pragma unroll
            for (int mt = 0; mt < 4; mt++) {
                h8 av = *(const h8*)(y1L + (mt * 16 + rl) * Y1S + kk * 32 + quad * 8);
                acc2[mt] = MFMA16(av, cf, acc2[mt]);
            }
            cf = nf;
        }
    }

    // ---- phase 4: h_short = relu((a .* window[-8:]) @ sw + sb), K=512 N=128 ----
    f4 accS[4];
#pragma unroll
    for (int mt = 0; mt < 4; mt++)
#pragma unroll
        for (int r = 0; r < 4; r++) accS[mt][r] = 0.f;
    {
        const h8* swv = (const h8*)swp;
        h8 cf = swv[wv * 64 + lane];
#pragma unroll 2
        for (int kk = 0; kk < 16; kk++) {
            int kn = (kk + 1) & 15;
            h8 nf = swv[(kn * 8 + wv) * 64 + lane];
            const int wf = 24 + (kk >> 1);
            const int c0 = ((kk & 1) << 5) + quad * 8;
#pragma unroll
            for (int mt = 0; mt < 4; mt++) {
                int m = mt * 16 + rl;
                h8 xv = *(const h8*)(xcL + (m + wf) * XCS + c0);
                h8 af = xv * avr[mt][kk & 1];
                accS[mt] = MFMA16(af, cf, accS[mt]);
            }
            cf = nf;
        }
    }
    __syncthreads();  // phase-3 reads of y1L done before overwrite

    // ---- phase 5a: hL[m][0:128]=relu(h2), hL[m][128:256]=relu(h_short) ----
    {
        int n = wv * 16 + rl;
        float bb2 = b2[n], bbs = sb[n];
#pragma unroll
        for (int mt = 0; mt < 4; mt++)
#pragma unroll
            for (int r = 0; r < 4; r++) {
                int m = mt * 16 + quad * 4 + r;
                y1L[m * Y1S + n]       = to_h(fmaxf(acc2[mt][r] + bb2, 0.f));
                y1L[m * Y1S + 128 + n] = to_h(fmaxf(accS[mt][r] + bbs, 0.f));
            }
    }
    __syncthreads();

    // ---- phase 5b: out = sigmoid(h @ wo + bo), 128 threads ----
    if (tid < 128) {
        int m = tid >> 1, o = tid & 1;
        float z = bo[o];
        const half_t* hrow = y1L + m * Y1S;
        for (int nb = 0; nb < 32; nb++) {
            h8 hv = *(const h8*)(hrow + nb * 8);
#pragma unroll
            for (int q = 0; q < 8; q++)
                z += (float)hv[q] * woL[(nb * 8 + q) * 2 + o];
        }
        z = fminf(fmaxf(z, -30.f), 30.f);
        float sg = 1.f / (1.f + __expf(-z));
        out[((size_t)(b * 4096 + t0 + m)) * 2 + o] = sg;
    }
}

extern "C" void kernel_launch(void* const* d_in, const int* in_sizes, int n_in,
                              void* d_out, int out_size, void* d_ws, size_t ws_size,
                              hipStream_t stream) {
    const float* x      = (const float*)d_in[0];
    const float* conv_w = (const float*)d_in[1];
    const float* conv_b = (const float*)d_in[2];
    const float* se_w1  = (const float*)d_in[3];
    const float* se_b1  = (const float*)d_in[4];
    const float* se_w2  = (const float*)d_in[5];
    const float* se_b2  = (const float*)d_in[6];
    const float* w1     = (const float*)d_in[7];
    const float* b1     = (const float*)d_in[8];
    const float* w2     = (const float*)d_in[9];
    const float* b2     = (const float*)d_in[10];
    const float* sw     = (const float*)d_in[11];
    const float* sb     = (const float*)d_in[12];
    const float* wo     = (const float*)d_in[13];
    const float* bo     = (const float*)d_in[14];
    half_t* wsH = (half_t*)d_ws;

    hipLaunchKernelGGL(pack_k, dim3(337), dim3(256), 0, stream, w1, w2, sw, conv_w, wsH);
    hipLaunchKernelGGL(beat_main, dim3(512), dim3(512), 0, stream,
                       x, conv_b, se_w1, se_b1, se_w2, se_b2, b1, b2, sb, wo, bo,
                       wsH, wsH + 524288, wsH + 557056, wsH + 622592,
                       (float*)d_out);
}